// Round 14
// baseline (650.851 us; speedup 1.0000x reference)
//
#include <hip/hip_runtime.h>

typedef __bf16 bf16x8 __attribute__((ext_vector_type(8)));
typedef float f32x4 __attribute__((ext_vector_type(4)));
typedef float f32x16 __attribute__((ext_vector_type(16)));
typedef unsigned short ushort_t;

__device__ __forceinline__ ushort_t f2bf(float f) {
  unsigned int u = __float_as_uint(f);
  u += 0x7fffu + ((u >> 16) & 1u);
  return (ushort_t)(u >> 16);
}
__device__ __forceinline__ float bf2f(ushort_t u) {
  return __uint_as_float(((unsigned int)u) << 16);
}

// async global->LDS, 16 bytes per lane (dest = wave-uniform base + lane*16)
__device__ __forceinline__ void gl_lds16(const ushort_t* g, const char* l) {
  __builtin_amdgcn_global_load_lds(
      (const __attribute__((address_space(1))) void*)g,
      (__attribute__((address_space(3))) void*)l, 16, 0, 0);
}

__global__ __launch_bounds__(256) void fill_k(float* __restrict__ p, long n, float v) {
  long i = (long)blockIdx.x * 256 + threadIdx.x;
  if (i < n) p[i] = v;
}

// ---------------- batched transpose: fp32 Z x R x C  ->  bf16 Z x C x R ----
__global__ __launch_bounds__(256) void transpose_w(const float* __restrict__ in,
                                                   ushort_t* __restrict__ out,
                                                   int R, int C) {
  __shared__ float tile[32][33];
  const float* inb = in + (long)blockIdx.z * R * C;
  ushort_t* outb = out + (long)blockIdx.z * R * C;
  int r0 = blockIdx.x * 32, c0 = blockIdx.y * 32;
  int tx = threadIdx.x & 31, ty = threadIdx.x >> 5;
#pragma unroll
  for (int i = ty; i < 32; i += 8) tile[i][tx] = inb[(long)(r0 + i) * C + (c0 + tx)];
  __syncthreads();
#pragma unroll
  for (int i = ty; i < 32; i += 8) outb[(long)(c0 + i) * R + (r0 + tx)] = f2bf(tile[tx][i]);
}

// ---------------- layernorm: one row (D=1024) per 256-thread block ---------
template <bool BFIN>
__global__ __launch_bounds__(256) void ln_k(const void* __restrict__ xin,
                                            const float* __restrict__ g,
                                            const float* __restrict__ b,
                                            ushort_t* __restrict__ outU) {
  __shared__ float red[8];
  long row = blockIdx.x;
  int tid = threadIdx.x;
  float4 v;
  if constexpr (BFIN) {
    ushort4 u4 = ((const ushort4*)((const ushort_t*)xin + row * 1024))[tid];
    v = make_float4(bf2f(u4.x), bf2f(u4.y), bf2f(u4.z), bf2f(u4.w));
  } else {
    v = ((const float4*)((const float*)xin + row * 1024))[tid];
  }
  float s = v.x + v.y + v.z + v.w;
#pragma unroll
  for (int off = 32; off; off >>= 1) s += __shfl_xor(s, off);
  int w = tid >> 6;
  if ((tid & 63) == 0) red[w] = s;
  __syncthreads();
  float mean = (red[0] + red[1] + red[2] + red[3]) * (1.0f / 1024.0f);
  float dx = v.x - mean, dy = v.y - mean, dz = v.z - mean, dw = v.w - mean;
  float s2 = dx * dx + dy * dy + dz * dz + dw * dw;
#pragma unroll
  for (int off = 32; off; off >>= 1) s2 += __shfl_xor(s2, off);
  if ((tid & 63) == 0) red[4 + w] = s2;
  __syncthreads();
  float var = (red[4] + red[5] + red[6] + red[7]) * (1.0f / 1024.0f);
  float rstd = rsqrtf(var + 1e-5f);
  int c = tid * 4;
  ushort4 u;
  u.x = f2bf(dx * rstd * g[c + 0] + b[c + 0]);
  u.y = f2bf(dy * rstd * g[c + 1] + b[c + 1]);
  u.z = f2bf(dz * rstd * g[c + 2] + b[c + 2]);
  u.w = f2bf(dw * rstd * g[c + 3] + b[c + 3]);
  ((ushort4*)(outU + row * 1024))[tid] = u;
}

// ---------------- 256x256 8-wave 8-phase bf16 GEMM (BK=64, 32x32x16 MFMA) --
// r10 staging/sync structure; inner math swapped to v_mfma_f32_32x32x16_bf16
// (2382 TF ceiling vs 2075, half the instruction count per phase).
// A-frag: lane reads row=lane&31, k-slot = kb*2+(lane>>5) (bijective per row
// with the XOR-8 swizzle -> conflict-free). C/D: row=(reg&3)+8*(reg>>2)+
// 4*(lane>>5), col=lane&31 [m74/m101].
// Epilogues: 3: bf16 relu(acc+bias)  4: fused QKV (q,k [b,h,t,e]; v [b,h,e,t])
//            5: bf16 acc+bias+res    6: fp32 acc+bias+res -> d_out
template <int EPI>
__global__ __launch_bounds__(512, 2) void gemm256(const ushort_t* __restrict__ A,
                                                  const ushort_t* __restrict__ Bt,
                                                  int M, int N, int K, int NBC,
                                                  const float* __restrict__ bias,
                                                  const ushort_t* __restrict__ resU,
                                                  float* __restrict__ outF,
                                                  ushort_t* __restrict__ outU,
                                                  ushort_t* __restrict__ outU2,
                                                  ushort_t* __restrict__ outU3) {
  __shared__ __align__(16) char lds[131072];
  const int tid = threadIdx.x;
  const int lane = tid & 63;
  const int w = tid >> 6;            // 0..7
  const int wr = w >> 2, wc = w & 3; // 2 x 4 wave grid
  const int l31 = lane & 31, h = lane >> 5, l7 = lane & 7;
  const int g = lane >> 4, lr = lane & 15;   // for staging/epilogue readback
  const int cpx = gridDim.x >> 3;
  const int wg = (blockIdx.x & 7) * cpx + (blockIdx.x >> 3);
  const long m0 = (long)(wg / NBC) * 256;
  const long n0 = (long)(wg % NBC) * 256;
  // staging source (pre-swizzled so linear gl_lds dest yields swizzled LDS)
  const int srow = tid >> 3;                  // 0..63 within an 8KB issue
  const int sslot = (tid & 7) ^ (srow & 7);   // logical 16B slot to fetch
  const ushort_t* sA = A + (m0 + srow) * (long)K + sslot * 8;
  const ushort_t* sB = Bt + (n0 + srow) * (long)K + sslot * 8;
  const int dA = tid * 16;
  const int dB = 32768 + tid * 16;
  // ds_read bases (32x32 operand layout): row = base + mb*32 + l31,
  // byte = row*128 + phys*16, phys = (kb*2 + h) ^ (row&7) = (kb*2+h) ^ l7
  const int arow = (wr * 128 + l31) * 128;
  const int brow = 32768 + (wc * 64 + l31) * 128;
  int axk[4];
#pragma unroll
  for (int kb = 0; kb < 4; ++kb) axk[kb] = ((kb * 2 + h) ^ l7) * 16;
  const int NT = K >> 6;

  f32x16 acc[4][2] = {};
  bf16x8 aR[2][4], bR[2][4];
  const char* rb;

#define STAGE_A(tile, half) do {                                          \
    const long _ko = (long)(tile) * 64;                                   \
    char* _d = lds + (((tile) & 1) << 16) + ((half) << 14) + dA;          \
    gl_lds16(sA + _ko + (long)(2 * (half)) * 64 * K, _d);                 \
    gl_lds16(sA + _ko + (long)(2 * (half) + 1) * 64 * K, _d + 8192);      \
  } while (0)
#define STAGE_B(tile, half) do {                                          \
    const long _ko = (long)(tile) * 64;                                   \
    char* _d = lds + (((tile) & 1) << 16) + ((half) << 14) + dB;          \
    gl_lds16(sB + _ko + (long)(2 * (half)) * 64 * K, _d);                 \
    gl_lds16(sB + _ko + (long)(2 * (half) + 1) * 64 * K, _d + 8192);      \
  } while (0)
#define RD_A(MB2) do {                                                    \
    _Pragma("unroll") for (int kb = 0; kb < 4; ++kb) {                    \
      aR[0][kb] = *(const bf16x8*)(rb + arow + (MB2) * 4096 + axk[kb]);   \
      aR[1][kb] = *(const bf16x8*)(rb + arow + ((MB2) + 1) * 4096 + axk[kb]); \
    } } while (0)
#define RD_B(NB) do {                                                     \
    _Pragma("unroll") for (int kb = 0; kb < 4; ++kb)                      \
      bR[NB][kb] = *(const bf16x8*)(rb + brow + (NB) * 4096 + axk[kb]);   \
  } while (0)
#define QUAD(MB, NB) do {                                                 \
    __builtin_amdgcn_s_setprio(1);                                        \
    _Pragma("unroll") for (int kb = 0; kb < 4; ++kb) {                    \
      acc[(MB)][NB] = __builtin_amdgcn_mfma_f32_32x32x16_bf16(aR[0][kb], bR[NB][kb], acc[(MB)][NB], 0, 0, 0); \
      acc[(MB) + 1][NB] = __builtin_amdgcn_mfma_f32_32x32x16_bf16(aR[1][kb], bR[NB][kb], acc[(MB) + 1][NB], 0, 0, 0); \
    }                                                                     \
    __builtin_amdgcn_s_setprio(0); } while (0)
#define LGKM0 do {                                                        \
    asm volatile("s_waitcnt lgkmcnt(0)" ::: "memory");                    \
    __builtin_amdgcn_sched_barrier(0); } while (0)

  // ---- prologue: 7 half-tiles, oldest-first; drain tile 0 (8 loads) ----
  STAGE_B(0, 0); STAGE_B(0, 1); STAGE_A(0, 0); STAGE_A(0, 1);
  STAGE_B(1, 0); STAGE_B(1, 1); STAGE_A(1, 0);
  asm volatile("s_waitcnt vmcnt(6)" ::: "memory");
  __builtin_amdgcn_s_barrier();

  for (int t = 0; t < NT; t += 2) {
    const bool s2 = (t + 2 < NT), s3 = (t + 3 < NT);
    // ===================== tile t (buf0) =====================
    rb = lds;
    RD_A(0);
    RD_B(0);
    STAGE_A(t + 1, 1);
    asm volatile("s_waitcnt lgkmcnt(8)" ::: "memory");
    __builtin_amdgcn_s_barrier();
    LGKM0;
    QUAD(0, 0);
    __builtin_amdgcn_s_barrier();
    RD_B(1);
    __builtin_amdgcn_s_barrier();
    LGKM0;
    QUAD(0, 1);
    __builtin_amdgcn_s_barrier();
    if (s2) STAGE_B(t + 2, 0);
    RD_A(2);
    __builtin_amdgcn_s_barrier();
    LGKM0;
    QUAD(2, 1);
    __builtin_amdgcn_s_barrier();
    if (s2) { STAGE_B(t + 2, 1); STAGE_A(t + 2, 0); }
    __builtin_amdgcn_s_barrier();
    QUAD(2, 0);
    if (s2) asm volatile("s_waitcnt vmcnt(6)" ::: "memory");
    else    asm volatile("s_waitcnt vmcnt(0)" ::: "memory");
    __builtin_amdgcn_s_barrier();
    // ===================== tile t+1 (buf1) =====================
    rb = lds + 65536;
    RD_A(0);
    RD_B(0);
    if (s2) STAGE_A(t + 2, 1);
    asm volatile("s_waitcnt lgkmcnt(8)" ::: "memory");
    __builtin_amdgcn_s_barrier();
    LGKM0;
    QUAD(0, 0);
    __builtin_amdgcn_s_barrier();
    RD_B(1);
    __builtin_amdgcn_s_barrier();
    LGKM0;
    QUAD(0, 1);
    __builtin_amdgcn_s_barrier();
    if (s3) STAGE_B(t + 3, 0);
    RD_A(2);
    __builtin_amdgcn_s_barrier();
    LGKM0;
    QUAD(2, 1);
    __builtin_amdgcn_s_barrier();
    if (s3) { STAGE_B(t + 3, 1); STAGE_A(t + 3, 0); }
    __builtin_amdgcn_s_barrier();
    QUAD(2, 0);
    if (s3) asm volatile("s_waitcnt vmcnt(6)" ::: "memory");
    else    asm volatile("s_waitcnt vmcnt(0)" ::: "memory");
    __builtin_amdgcn_s_barrier();
  }
#undef STAGE_A
#undef STAGE_B
#undef RD_A
#undef RD_B
#undef QUAD
#undef LGKM0

  // ---- epilogue. C/D 32x32 layout: row=(reg&3)+8*(reg>>2)+4*h, col=l31.
  // Repack via LDS (dead after K-loop); phys_col = col ^ (((row>>2)&3)<<3).
  if constexpr (EPI == 3 || EPI == 5) {
    ushort_t* l16 = (ushort_t*)lds;
#pragma unroll
    for (int mb = 0; mb < 4; ++mb)
#pragma unroll
      for (int nb = 0; nb < 2; ++nb) {
        int col = wc * 64 + nb * 32 + l31;
        long gcol = n0 + col;
#pragma unroll
        for (int reg = 0; reg < 16; ++reg) {
          int row = wr * 128 + mb * 32 + (reg & 3) + 8 * (reg >> 2) + 4 * h;
          float v = acc[mb][nb][reg] + bias[gcol];
          if constexpr (EPI == 3) v = fmaxf(v, 0.0f);
          else v += bf2f(resU[(m0 + row) * (long)N + gcol]);
          l16[row * 256 + (col ^ (((row >> 2) & 3) << 3))] = f2bf(v);
        }
      }
    __syncthreads();
#pragma unroll
    for (int k = 0; k < 16; ++k) {
      int c2 = tid + k * 512;
      int tt = c2 >> 5, off = c2 & 31;
      int pc = (off * 8) ^ ((((unsigned)tt >> 2) & 3) << 3);
      uint4 d = *(uint4*)&l16[tt * 256 + pc];
      *(uint4*)&outU[(m0 + tt) * (long)N + n0 + off * 8] = d;
    }
  } else if constexpr (EPI == 6) {
#pragma unroll
    for (int mb = 0; mb < 4; ++mb)
#pragma unroll
      for (int nb = 0; nb < 2; ++nb) {
        long col = n0 + wc * 64 + nb * 32 + l31;
#pragma unroll
        for (int reg = 0; reg < 16; ++reg) {
          long row = m0 + wr * 128 + mb * 32 + (reg & 3) + 8 * (reg >> 2) + 4 * h;
          long i = row * (long)N + col;
          outF[i] = acc[mb][nb][reg] + bias[col] + bf2f(resU[i]);
        }
      }
  } else {  // EPI == 4: fused QKV
    const int p = (int)(n0 >> 10);       // block-uniform: which of q/k/v
    const long bb2 = m0 >> 8;
    if (p < 2) {
      ushort_t* dst = (p == 0) ? outU : outU2;
      ushort_t* l16 = (ushort_t*)lds;
#pragma unroll
      for (int mb = 0; mb < 4; ++mb)
#pragma unroll
        for (int nb = 0; nb < 2; ++nb) {
          int col = wc * 64 + nb * 32 + l31;
#pragma unroll
          for (int reg = 0; reg < 16; ++reg) {
            int row = wr * 128 + mb * 32 + (reg & 3) + 8 * (reg >> 2) + 4 * h;
            l16[row * 256 + (col ^ (((row >> 2) & 3) << 3))] = f2bf(acc[mb][nb][reg]);
          }
        }
      __syncthreads();
      const int hh0 = (int)((n0 & 1023) >> 6);
#pragma unroll
      for (int k = 0; k < 16; ++k) {
        int c2 = tid + k * 512;
        int hh_l = c2 >> 11, tt = (c2 >> 3) & 255, off = c2 & 7;
        int col = hh_l * 64 + off * 8;
        int pc = col ^ ((((unsigned)tt >> 2) & 3) << 3);
        uint4 d = *(uint4*)&l16[tt * 256 + pc];
        *(uint4*)&dst[(((bb2 * 16 + hh0 + hh_l) * 256 + tt) << 6) + off * 8] = d;
      }
    } else {
      // V third: transpose 256x256 tile through LDS, then coalesced stores.
      unsigned int* l32 = (unsigned int*)lds;
#pragma unroll
      for (int mb = 0; mb < 4; ++mb)
#pragma unroll
        for (int nb = 0; nb < 2; ++nb) {
          int col = wc * 64 + nb * 32 + l31;
#pragma unroll
          for (int j = 0; j < 8; ++j) {
            int row = wr * 128 + mb * 32 + 2 * (j & 1) + 8 * (j >> 1) + 4 * h;  // even
            unsigned int pk = (unsigned int)f2bf(acc[mb][nb][2 * j]) |
                              ((unsigned int)f2bf(acc[mb][nb][2 * j + 1]) << 16);
            l32[col * 128 + ((row >> 1) ^ ((col & 7) << 2))] = pk;
          }
        }
      __syncthreads();
      const long vcol0 = (n0 & 1023);
#pragma unroll
      for (int k = 0; k < 16; ++k) {
        int c2 = tid + k * 512;           // 8192 16B-chunks total
        int e_l = c2 >> 5, k16 = c2 & 31;
        uint4 d = *(uint4*)&l32[e_l * 128 + ((k16 * 4) ^ ((e_l & 7) << 2))];
        long vc = vcol0 + e_l;
        long hh = vc >> 6, e = vc & 63;
        *(uint4*)&outU3[(((bb2 * 16 + hh) * 64 + e) << 8) + k16 * 8] = d;
      }
    }
  }
}

// ---------------- flash attention: 1 wave per (32 q rows, b, h) ------------
__global__ __launch_bounds__(64, 4) void attn_k(const ushort_t* __restrict__ q,
                                                const ushort_t* __restrict__ k,
                                                const ushort_t* __restrict__ vt,
                                                ushort_t* __restrict__ ao) {
  __shared__ __align__(16) ushort_t Ps[32][40];
  const int lane = threadIdx.x;
  const int g = lane >> 4, lr = lane & 15;
  const int blk = blockIdx.x;
  const int q8 = blk & 7;
  const int bh = blk >> 3;
  const int bb = bh >> 4, hh = bh & 15;
  const int q0 = q8 * 32;
  const ushort_t* qb = q + (long)bh * 256 * 64;
  const ushort_t* kb = k + (long)bh * 256 * 64;
  const ushort_t* vb = vt + (long)bh * 64 * 256;
  bf16x8 qf[2][2];
#pragma unroll
  for (int m = 0; m < 2; m++)
#pragma unroll
    for (int ks = 0; ks < 2; ks++)
      qf[m][ks] = *(const bf16x8*)(qb + (q0 + m * 16 + lr) * 64 + ks * 32 + g * 8);
  f32x4 o[2][4] = {};
  float mrow[2][4], lrow[2][4];
#pragma unroll
  for (int m = 0; m < 2; m++)
#pragma unroll
    for (int r = 0; r < 4; r++) { mrow[m][r] = -3.0e38f; lrow[m][r] = 0.0f; }
  const float sc2 = 0.04508422f;   // (1/32) * log2(e)
  const int nkb = q8 + 1;
  for (int kbk = 0; kbk < nkb; kbk++) {
    f32x4 s[2][2] = {};
#pragma unroll
    for (int ks = 0; ks < 2; ks++) {
      bf16x8 kf[2];
#pragma unroll
      for (int n = 0; n < 2; n++)
        kf[n] = *(const bf16x8*)(kb + (kbk * 32 + n * 16 + lr) * 64 + ks * 32 + g * 8);
#pragma unroll
      for (int m = 0; m < 2; m++)
#pragma unroll
        for (int n = 0; n < 2; n++)
          s[m][n] = __builtin_amdgcn_mfma_f32_16x16x32_bf16(qf[m][ks], kf[n], s[m][n], 0, 0, 0);
    }
    bf16x8 vf[4];
#pragma unroll
    for (int n = 0; n < 4; n++)
      vf[n] = *(const bf16x8*)(vb + (n * 16 + lr) * 256 + kbk * 32 + g * 8);
    if (kbk == q8) {
#pragma unroll
      for (int m = 0; m < 2; m++)
#pragma unroll
        for (int n = 0; n < 2; n++)
#pragma unroll
          for (int r = 0; r < 4; r++) {
            int row = q0 + m * 16 + g * 4 + r;
            int col = kbk * 32 + n * 16 + lr;
            s[m][n][r] = (col <= row) ? s[m][n][r] * sc2 : -3.0e38f;
          }
    } else {
#pragma unroll
      for (int m = 0; m < 2; m++)
#pragma unroll
        for (int n = 0; n < 2; n++)
#pragma unroll
          for (int r = 0; r < 4; r++) s[m][n][r] *= sc2;
    }
    float mx[2][4];
    float growth = -3.0e38f;
#pragma unroll
    for (int m = 0; m < 2; m++)
#pragma unroll
      for (int r = 0; r < 4; r++) {
        float v = fmaxf(s[m][0][r], s[m][1][r]);
#pragma unroll
        for (int off = 8; off; off >>= 1) v = fmaxf(v, __shfl_xor(v, off));
        mx[m][r] = v;
        growth = fmaxf(growth, v - mrow[m][r]);
      }
    if (__any(growth > 8.0f)) {
#pragma unroll
      for (int m = 0; m < 2; m++)
#pragma unroll
        for (int r = 0; r < 4; r++) {
          float mn = fmaxf(mrow[m][r], mx[m][r]);
          float al = exp2f(mrow[m][r] - mn);
          mrow[m][r] = mn;
          lrow[m][r] *= al;
#pragma unroll
          for (int n = 0; n < 4; n++) o[m][n][r] *= al;
        }
    }
#pragma unroll
    for (int m = 0; m < 2; m++)
#pragma unroll
      for (int r = 0; r < 4; r++) {
        float rs = 0.0f;
#pragma unroll
        for (int n = 0; n < 2; n++) {
          float p = exp2f(s[m][n][r] - mrow[m][r]);
          s[m][n][r] = p;
          rs += p;
        }
#pragma unroll
        for (int off = 8; off; off >>= 1) rs += __shfl_xor(rs, off);
        lrow[m][r] += rs;
      }
#pragma unroll
    for (int m = 0; m < 2; m++)
#pragma unroll
      for (int n = 0; n < 2; n++)
#pragma unroll
        for (int r = 0; r < 4; r++)
          Ps[m * 16 + g * 4 + r][n * 16 + lr] = f2bf(s[m][n][r]);
#pragma unroll
    for (int m = 0; m < 2; m++) {
      bf16x8 pa = *(const bf16x8*)&Ps[m * 16 + lr][g * 8];
#pragma unroll
      for (int n = 0; n < 4; n++)
        o[m][n] = __builtin_amdgcn_mfma_f32_16x16x32_bf16(pa, vf[n], o[m][n], 0, 0, 0);
    }
  }
#pragma unroll
  for (int m = 0; m < 2; m++)
#pragma unroll
    for (int r = 0; r < 4; r++) {
      float inv = 1.0f / lrow[m][r];
      long t = q0 + m * 16 + g * 4 + r;
#pragma unroll
      for (int n = 0; n < 4; n++) {
        long e = n * 16 + lr;
        ao[((long)bb * 256 + t) * 1024 + hh * 64 + e] = f2bf(o[m][n][r] * inv);
      }
    }
}

// ---------------- launch ---------------------------------------------------
// Workspace (MB offsets, 184 MB): wqt@0 wkt@2 wvt@4 (fused N=3072 B^T) wpt@6
// w1t@8 w2t@16; hb@24 (bf16 h, then h2); qbf@56 kbf@88 vtb@120 atb@152.
// yb (bf16 y) reuses qbf@56; ff1@56 (128MB) after LN2. d_out: fp32, FF2 only.
extern "C" void kernel_launch(void* const* d_in, const int* in_sizes, int n_in,
                              void* d_out, int out_size, void* d_ws, size_t ws_size,
                              hipStream_t stream) {
  const float* x     = (const float*)d_in[0];
  const float* ln1g  = (const float*)d_in[1];
  const float* ln1b  = (const float*)d_in[2];
  const float* Wq    = (const float*)d_in[3];
  const float* Wk    = (const float*)d_in[4];
  const float* Wv    = (const float*)d_in[5];
  const float* Wproj = (const float*)d_in[6];
  const float* bproj = (const float*)d_in[7];
  const float* ln2g  = (const float*)d_in[8];
  const float* ln2b  = (const float*)d_in[9];
  const float* W1    = (const float*)d_in[10];
  const float* b1    = (const float*)d_in[11];
  const float* W2    = (const float*)d_in[12];
  const float* b2    = (const float*)d_in[13];

  const long NEED = 184L << 20;
  if (ws_size < (size_t)NEED) {
    fill_k<<<(out_size + 255) / 256, 256, 0, stream>>>((float*)d_out, out_size,
                                                       (float)(ws_size >> 20));
    return;
  }

  char* ws = (char*)d_ws;
  const long MB = 1 << 20;
  ushort_t* wqt = (ushort_t*)(ws + 0 * MB);   // [0,6MB) = fused QKV B^T
  ushort_t* wkt = (ushort_t*)(ws + 2 * MB);
  ushort_t* wvt = (ushort_t*)(ws + 4 * MB);
  ushort_t* wpt = (ushort_t*)(ws + 6 * MB);
  ushort_t* w1t = (ushort_t*)(ws + 8 * MB);
  ushort_t* w2t = (ushort_t*)(ws + 16 * MB);
  ushort_t* hb  = (ushort_t*)(ws + 24 * MB);  // h, later h2 (bf16)
  ushort_t* qbf = (ushort_t*)(ws + 56 * MB);
  ushort_t* kbf = (ushort_t*)(ws + 88 * MB);
  ushort_t* vtb = (ushort_t*)(ws + 120 * MB);
  ushort_t* atb = (ushort_t*)(ws + 152 * MB);
  ushort_t* yb  = (ushort_t*)(ws + 56 * MB);  // y (bf16), reuses qbf
  ushort_t* ff1 = (ushort_t*)(ws + 56 * MB);  // reuses qbf..atb after LN2

  transpose_w<<<dim3(32, 2, 16), 256, 0, stream>>>(Wq, wqt, 1024, 64);
  transpose_w<<<dim3(32, 2, 16), 256, 0, stream>>>(Wk, wkt, 1024, 64);
  transpose_w<<<dim3(32, 2, 16), 256, 0, stream>>>(Wv, wvt, 1024, 64);
  transpose_w<<<dim3(32, 32, 1), 256, 0, stream>>>(Wproj, wpt, 1024, 1024);
  transpose_w<<<dim3(32, 128, 1), 256, 0, stream>>>(W1, w1t, 1024, 4096);
  transpose_w<<<dim3(128, 32, 1), 256, 0, stream>>>(W2, w2t, 4096, 1024);

  // h = LN1(x) -> bf16
  ln_k<false><<<16384, 256, 0, stream>>>(x, ln1g, ln1b, hb);
  // fused q/k/v projection (M=16384, N=3072, K=1024; grid 64x12=768)
  gemm256<4><<<768, 512, 0, stream>>>(hb, wqt, 16384, 3072, 1024, 12,
                                      nullptr, nullptr, nullptr, qbf, kbf, vtb);
  attn_k<<<8192, 64, 0, stream>>>(qbf, kbf, vtb, atb);
  // y = h + attn @ Wproj + bproj  (bf16 out into yb)
  gemm256<5><<<256, 512, 0, stream>>>(atb, wpt, 16384, 1024, 1024, 4,
                                      bproj, hb, nullptr, yb, nullptr, nullptr);
  // h2 = LN2(y) -> hb (h dead)
  ln_k<true><<<16384, 256, 0, stream>>>(yb, ln2g, ln2b, hb);
  // ff1 = relu(h2 @ W1 + b1)  (N=4096; grid 64x16=1024)
  gemm256<3><<<1024, 512, 0, stream>>>(hb, w1t, 16384, 4096, 1024, 16,
                                       b1, nullptr, nullptr, ff1, nullptr, nullptr);
  // out = h2 + ff1 @ W2 + b2  (fp32 into d_out; K=4096, grid 64x4=256)
  gemm256<6><<<256, 512, 0, stream>>>(ff1, w2t, 16384, 1024, 4096, 4,
                                      b2, hb, (float*)d_out, nullptr, nullptr, nullptr);
}

// Round 15
// 575.517 us; speedup vs baseline: 1.1309x; 1.1309x over previous
//
#include <hip/hip_runtime.h>

typedef __bf16 bf16x8 __attribute__((ext_vector_type(8)));
typedef float f32x4 __attribute__((ext_vector_type(4)));
typedef unsigned short ushort_t;

__device__ __forceinline__ ushort_t f2bf(float f) {
  unsigned int u = __float_as_uint(f);
  u += 0x7fffu + ((u >> 16) & 1u);
  return (ushort_t)(u >> 16);
}
__device__ __forceinline__ float bf2f(ushort_t u) {
  return __uint_as_float(((unsigned int)u) << 16);
}

// async global->LDS, 16 bytes per lane (dest = wave-uniform base + lane*16)
__device__ __forceinline__ void gl_lds16(const ushort_t* g, const char* l) {
  __builtin_amdgcn_global_load_lds(
      (const __attribute__((address_space(1))) void*)g,
      (__attribute__((address_space(3))) void*)l, 16, 0, 0);
}

__global__ __launch_bounds__(256) void fill_k(float* __restrict__ p, long n, float v) {
  long i = (long)blockIdx.x * 256 + threadIdx.x;
  if (i < n) p[i] = v;
}

// ---------------- batched transpose: fp32 Z x R x C  ->  bf16 Z x C x R ----
__global__ __launch_bounds__(256) void transpose_w(const float* __restrict__ in,
                                                   ushort_t* __restrict__ out,
                                                   int R, int C) {
  __shared__ float tile[32][33];
  const float* inb = in + (long)blockIdx.z * R * C;
  ushort_t* outb = out + (long)blockIdx.z * R * C;
  int r0 = blockIdx.x * 32, c0 = blockIdx.y * 32;
  int tx = threadIdx.x & 31, ty = threadIdx.x >> 5;
#pragma unroll
  for (int i = ty; i < 32; i += 8) tile[i][tx] = inb[(long)(r0 + i) * C + (c0 + tx)];
  __syncthreads();
#pragma unroll
  for (int i = ty; i < 32; i += 8) outb[(long)(c0 + i) * R + (r0 + tx)] = f2bf(tile[tx][i]);
}

// ---------------- layernorm: one row (D=1024) per 256-thread block ---------
template <bool BFIN>
__global__ __launch_bounds__(256) void ln_k(const void* __restrict__ xin,
                                            const float* __restrict__ g,
                                            const float* __restrict__ b,
                                            ushort_t* __restrict__ outU) {
  __shared__ float red[8];
  long row = blockIdx.x;
  int tid = threadIdx.x;
  float4 v;
  if constexpr (BFIN) {
    ushort4 u4 = ((const ushort4*)((const ushort_t*)xin + row * 1024))[tid];
    v = make_float4(bf2f(u4.x), bf2f(u4.y), bf2f(u4.z), bf2f(u4.w));
  } else {
    v = ((const float4*)((const float*)xin + row * 1024))[tid];
  }
  float s = v.x + v.y + v.z + v.w;
#pragma unroll
  for (int off = 32; off; off >>= 1) s += __shfl_xor(s, off);
  int w = tid >> 6;
  if ((tid & 63) == 0) red[w] = s;
  __syncthreads();
  float mean = (red[0] + red[1] + red[2] + red[3]) * (1.0f / 1024.0f);
  float dx = v.x - mean, dy = v.y - mean, dz = v.z - mean, dw = v.w - mean;
  float s2 = dx * dx + dy * dy + dz * dz + dw * dw;
#pragma unroll
  for (int off = 32; off; off >>= 1) s2 += __shfl_xor(s2, off);
  if ((tid & 63) == 0) red[4 + w] = s2;
  __syncthreads();
  float var = (red[4] + red[5] + red[6] + red[7]) * (1.0f / 1024.0f);
  float rstd = rsqrtf(var + 1e-5f);
  int c = tid * 4;
  ushort4 u;
  u.x = f2bf(dx * rstd * g[c + 0] + b[c + 0]);
  u.y = f2bf(dy * rstd * g[c + 1] + b[c + 1]);
  u.z = f2bf(dz * rstd * g[c + 2] + b[c + 2]);
  u.w = f2bf(dw * rstd * g[c + 3] + b[c + 3]);
  ((ushort4*)(outU + row * 1024))[tid] = u;
}

// ---------------- 256x256 8-wave 8-phase bf16 GEMM (BK=64, r10 proven) -----
// Epilogues: 3: bf16 relu(acc+bias)  4: fused QKV (q,k [b,h,t,e]; v [b,h,e,t])
//            5: bf16 acc+bias+res    6: fp32 acc+bias+res -> d_out
template <int EPI>
__global__ __launch_bounds__(512, 2) void gemm256(const ushort_t* __restrict__ A,
                                                  const ushort_t* __restrict__ Bt,
                                                  int M, int N, int K, int NBC,
                                                  const float* __restrict__ bias,
                                                  const ushort_t* __restrict__ resU,
                                                  float* __restrict__ outF,
                                                  ushort_t* __restrict__ outU,
                                                  ushort_t* __restrict__ outU2,
                                                  ushort_t* __restrict__ outU3) {
  __shared__ __align__(16) char lds[131072];
  const int tid = threadIdx.x;
  const int lane = tid & 63;
  const int w = tid >> 6;            // 0..7
  const int wr = w >> 2, wc = w & 3; // 2 x 4 wave grid
  const int g = lane >> 4, lr = lane & 15;
  const int cpx = gridDim.x >> 3;
  const int wg = (blockIdx.x & 7) * cpx + (blockIdx.x >> 3);
  const long m0 = (long)(wg / NBC) * 256;
  const long n0 = (long)(wg % NBC) * 256;
  // staging source (pre-swizzled so linear gl_lds dest yields swizzled LDS)
  const int srow = tid >> 3;                  // 0..63 within an 8KB issue
  const int sslot = (tid & 7) ^ (srow & 7);   // logical 16B slot to fetch
  const ushort_t* sA = A + (m0 + srow) * (long)K + sslot * 8;
  const ushort_t* sB = Bt + (n0 + srow) * (long)K + sslot * 8;
  const int dA = tid * 16;
  const int dB = 32768 + tid * 16;
  // ds_read bases: row-major [256][64]x2B per region, phys slot = log^(row&7)
  const int abase = (wr * 128 + lr) * 128;
  const int bbase = 32768 + (wc * 64 + lr) * 128;
  const int s0 = g ^ (lr & 7);         // ks=0: logical slot g
  const int s1 = (4 + g) ^ (lr & 7);   // ks=1: logical slot 4+g
  const int NT = K >> 6;

  f32x4 acc[8][4] = {};
  bf16x8 aR[4][2], bR[4][2];
  const char* rb;

#define STAGE_A(tile, half) do {                                          \
    const long _ko = (long)(tile) * 64;                                   \
    char* _d = lds + (((tile) & 1) << 16) + ((half) << 14) + dA;          \
    gl_lds16(sA + _ko + (long)(2 * (half)) * 64 * K, _d);                 \
    gl_lds16(sA + _ko + (long)(2 * (half) + 1) * 64 * K, _d + 8192);      \
  } while (0)
#define STAGE_B(tile, half) do {                                          \
    const long _ko = (long)(tile) * 64;                                   \
    char* _d = lds + (((tile) & 1) << 16) + ((half) << 14) + dB;          \
    gl_lds16(sB + _ko + (long)(2 * (half)) * 64 * K, _d);                 \
    gl_lds16(sB + _ko + (long)(2 * (half) + 1) * 64 * K, _d + 8192);      \
  } while (0)
#define RD_A(base_mf) do {                                                \
    _Pragma("unroll") for (int mf = 0; mf < 4; ++mf) {                    \
      aR[mf][0] = *(const bf16x8*)(rb + abase + ((base_mf) + mf) * 2048 + s0 * 16); \
      aR[mf][1] = *(const bf16x8*)(rb + abase + ((base_mf) + mf) * 2048 + s1 * 16); \
    } } while (0)
#define RD_B2(base_nf) do {                                               \
    _Pragma("unroll") for (int nf = 0; nf < 2; ++nf) {                    \
      bR[(base_nf) + nf][0] = *(const bf16x8*)(rb + bbase + ((base_nf) + nf) * 2048 + s0 * 16); \
      bR[(base_nf) + nf][1] = *(const bf16x8*)(rb + bbase + ((base_nf) + nf) * 2048 + s1 * 16); \
    } } while (0)
#define QUAD(MB, NB) do {                                                 \
    __builtin_amdgcn_s_setprio(1);                                        \
    _Pragma("unroll") for (int mf = 0; mf < 4; ++mf)                      \
      _Pragma("unroll") for (int nf = 0; nf < 2; ++nf) {                  \
        acc[(MB) + mf][(NB) + nf] = __builtin_amdgcn_mfma_f32_16x16x32_bf16(aR[mf][0], bR[(NB) + nf][0], acc[(MB) + mf][(NB) + nf], 0, 0, 0); \
        acc[(MB) + mf][(NB) + nf] = __builtin_amdgcn_mfma_f32_16x16x32_bf16(aR[mf][1], bR[(NB) + nf][1], acc[(MB) + mf][(NB) + nf], 0, 0, 0); \
      }                                                                   \
    __builtin_amdgcn_s_setprio(0); } while (0)
#define LGKM0 do {                                                        \
    asm volatile("s_waitcnt lgkmcnt(0)" ::: "memory");                    \
    __builtin_amdgcn_sched_barrier(0); } while (0)

  // ---- prologue: 7 half-tiles, oldest-first; drain tile 0 (8 loads) ----
  STAGE_B(0, 0); STAGE_B(0, 1); STAGE_A(0, 0); STAGE_A(0, 1);
  STAGE_B(1, 0); STAGE_B(1, 1); STAGE_A(1, 0);
  asm volatile("s_waitcnt vmcnt(6)" ::: "memory");
  __builtin_amdgcn_s_barrier();

  for (int t = 0; t < NT; t += 2) {
    const bool s2 = (t + 2 < NT), s3 = (t + 3 < NT);
    // ===================== tile t (buf0) =====================
    rb = lds;
    RD_A(0);
    RD_B2(0);
    STAGE_A(t + 1, 1);
    asm volatile("s_waitcnt lgkmcnt(8)" ::: "memory");
    __builtin_amdgcn_s_barrier();
    LGKM0;
    QUAD(0, 0);
    __builtin_amdgcn_s_barrier();
    RD_B2(2);
    __builtin_amdgcn_s_barrier();
    LGKM0;
    QUAD(0, 2);
    __builtin_amdgcn_s_barrier();
    if (s2) STAGE_B(t + 2, 0);
    RD_A(4);
    __builtin_amdgcn_s_barrier();
    LGKM0;
    QUAD(4, 2);
    __builtin_amdgcn_s_barrier();
    if (s2) { STAGE_B(t + 2, 1); STAGE_A(t + 2, 0); }
    __builtin_amdgcn_s_barrier();
    QUAD(4, 0);
    if (s2) asm volatile("s_waitcnt vmcnt(6)" ::: "memory");
    else    asm volatile("s_waitcnt vmcnt(0)" ::: "memory");
    __builtin_amdgcn_s_barrier();
    // ===================== tile t+1 (buf1) =====================
    rb = lds + 65536;
    RD_A(0);
    RD_B2(0);
    if (s2) STAGE_A(t + 2, 1);
    asm volatile("s_waitcnt lgkmcnt(8)" ::: "memory");
    __builtin_amdgcn_s_barrier();
    LGKM0;
    QUAD(0, 0);
    __builtin_amdgcn_s_barrier();
    RD_B2(2);
    __builtin_amdgcn_s_barrier();
    LGKM0;
    QUAD(0, 2);
    __builtin_amdgcn_s_barrier();
    if (s3) STAGE_B(t + 3, 0);
    RD_A(4);
    __builtin_amdgcn_s_barrier();
    LGKM0;
    QUAD(4, 2);
    __builtin_amdgcn_s_barrier();
    if (s3) { STAGE_B(t + 3, 1); STAGE_A(t + 3, 0); }
    __builtin_amdgcn_s_barrier();
    QUAD(4, 0);
    if (s3) asm volatile("s_waitcnt vmcnt(6)" ::: "memory");
    else    asm volatile("s_waitcnt vmcnt(0)" ::: "memory");
    __builtin_amdgcn_s_barrier();
  }
#undef STAGE_A
#undef STAGE_B
#undef RD_A
#undef RD_B2
#undef QUAD
#undef LGKM0

  // ---- epilogue. C/D frag layout col=lr, row=g*4+r [m89].
  if constexpr (EPI == 3 || EPI == 5) {
    ushort_t* l16 = (ushort_t*)lds;
#pragma unroll
    for (int mf = 0; mf < 8; ++mf)
#pragma unroll
      for (int nf = 0; nf < 4; ++nf) {
        int col = wc * 64 + nf * 16 + lr;
        long gcol = n0 + col;
#pragma unroll
        for (int r = 0; r < 4; ++r) {
          int row = wr * 128 + mf * 16 + g * 4 + r;
          float v = acc[mf][nf][r] + bias[gcol];
          if constexpr (EPI == 3) v = fmaxf(v, 0.0f);
          else v += bf2f(resU[(m0 + row) * (long)N + gcol]);
          l16[row * 256 + (col ^ (g << 3))] = f2bf(v);
        }
      }
    __syncthreads();
#pragma unroll
    for (int k = 0; k < 16; ++k) {
      int c = tid + k * 512;
      int tt = c >> 5, off = c & 31;
      int pc = (off * 8) ^ ((((unsigned)tt >> 2) & 3) << 3);
      uint4 d = *(uint4*)&l16[tt * 256 + pc];
      *(uint4*)&outU[(m0 + tt) * (long)N + n0 + off * 8] = d;
    }
  } else if constexpr (EPI == 6) {
#pragma unroll
    for (int mf = 0; mf < 8; ++mf)
#pragma unroll
      for (int nf = 0; nf < 4; ++nf)
#pragma unroll
        for (int r = 0; r < 4; ++r) {
          long row = m0 + wr * 128 + mf * 16 + g * 4 + r;
          long col = n0 + wc * 64 + nf * 16 + lr;
          long i = row * (long)N + col;
          outF[i] = acc[mf][nf][r] + bias[col] + bf2f(resU[i]);
        }
  } else {  // EPI == 4: fused QKV
    const int p = (int)(n0 >> 10);       // block-uniform: which of q/k/v
    const long bb2 = m0 >> 8;
    if (p < 2) {
      ushort_t* dst = (p == 0) ? outU : outU2;
      ushort_t* l16 = (ushort_t*)lds;
#pragma unroll
      for (int mf = 0; mf < 8; ++mf)
#pragma unroll
        for (int nf = 0; nf < 4; ++nf) {
          int col = wc * 64 + nf * 16 + lr;
#pragma unroll
          for (int r = 0; r < 4; ++r) {
            int row = wr * 128 + mf * 16 + g * 4 + r;
            l16[row * 256 + (col ^ (g << 3))] = f2bf(acc[mf][nf][r]);
          }
        }
      __syncthreads();
      const int hh0 = (int)((n0 & 1023) >> 6);
#pragma unroll
      for (int k = 0; k < 16; ++k) {
        int c = tid + k * 512;
        int hh_l = c >> 11, tt = (c >> 3) & 255, off = c & 7;
        int col = hh_l * 64 + off * 8;
        int pc = col ^ ((((unsigned)tt >> 2) & 3) << 3);
        uint4 d = *(uint4*)&l16[tt * 256 + pc];
        *(uint4*)&dst[(((bb2 * 16 + hh0 + hh_l) * 256 + tt) << 6) + off * 8] = d;
      }
    } else {
      // V third: transpose 256x256 tile through LDS, then coalesced stores.
      unsigned int* l32 = (unsigned int*)lds;
#pragma unroll
      for (int mf = 0; mf < 8; ++mf)
#pragma unroll
        for (int nf = 0; nf < 4; ++nf)
#pragma unroll
          for (int r2 = 0; r2 < 2; ++r2) {
            int row = wr * 128 + mf * 16 + g * 4 + r2 * 2;  // local tt (even)
            int col = wc * 64 + nf * 16 + lr;               // local v-col
            unsigned int pk = (unsigned int)f2bf(acc[mf][nf][r2 * 2]) |
                              ((unsigned int)f2bf(acc[mf][nf][r2 * 2 + 1]) << 16);
            l32[col * 128 + ((row >> 1) ^ ((col & 7) << 2))] = pk;
          }
      __syncthreads();
      const long vcol0 = (n0 & 1023);
#pragma unroll
      for (int k = 0; k < 16; ++k) {
        int c = tid + k * 512;           // 8192 16B-chunks total
        int e_l = c >> 5, k16 = c & 31;  // e-row, chunk within 512B row
        uint4 d = *(uint4*)&l32[e_l * 128 + ((k16 * 4) ^ ((e_l & 7) << 2))];
        long vc = vcol0 + e_l;
        long hh = vc >> 6, e = vc & 63;
        *(uint4*)&outU3[(((bb2 * 16 + hh) * 64 + e) << 8) + k16 * 8] = d;
      }
    }
  }
}

// ---------------- flash attention: 1 wave per (32 q rows, b, h) ------------
// q,k: [b,h,t,e] bf16; vt: [b,h,e,t] bf16; out: [b,t,h*64+e] bf16
// KVBLK=64: one softmax chain (max-reduce/exp/sum/rescale) per 64 KV cols ->
// avg serial iterations per wave 4.5 -> 2. Mask only in the last sub-block
// (col<=row covers diagonal AND the beyond-range half for even q8).
// launch_bounds(64,3): ~170 VGPR ceiling, no spill for s[2][4]+o[2][4]+qf.
__global__ __launch_bounds__(64, 3) void attn_k(const ushort_t* __restrict__ q,
                                                const ushort_t* __restrict__ k,
                                                const ushort_t* __restrict__ vt,
                                                ushort_t* __restrict__ ao) {
  __shared__ __align__(16) ushort_t Ps[32][72];
  const int lane = threadIdx.x;
  const int g = lane >> 4, lr = lane & 15;
  const int blk = blockIdx.x;
  const int q8 = blk & 7;          // which 32-row q block
  const int bh = blk >> 3;
  const int bb = bh >> 4, hh = bh & 15;
  const int q0 = q8 * 32;
  const ushort_t* qb = q + (long)bh * 256 * 64;
  const ushort_t* kb = k + (long)bh * 256 * 64;
  const ushort_t* vb = vt + (long)bh * 64 * 256;
  bf16x8 qf[2][2];
#pragma unroll
  for (int m = 0; m < 2; m++)
#pragma unroll
    for (int ks = 0; ks < 2; ks++)
      qf[m][ks] = *(const bf16x8*)(qb + (q0 + m * 16 + lr) * 64 + ks * 32 + g * 8);
  f32x4 o[2][4] = {};
  float mrow[2][4], lrow[2][4];
#pragma unroll
  for (int m = 0; m < 2; m++)
#pragma unroll
    for (int r = 0; r < 4; r++) { mrow[m][r] = -3.0e38f; lrow[m][r] = 0.0f; }
  const float sc2 = 0.04508422f;   // (1/32) * log2(e): softmax in exp2 domain
  const int nkb2 = (q8 >> 1) + 1;  // KV-64 blocks needed for rows < q0+32
  for (int kb2 = 0; kb2 < nkb2; kb2++) {
    const int c0 = kb2 * 64;
    // S = Q K^T over 64 cols
    f32x4 s[2][4] = {};
#pragma unroll
    for (int ks = 0; ks < 2; ks++) {
      bf16x8 kf[4];
#pragma unroll
      for (int n = 0; n < 4; n++)
        kf[n] = *(const bf16x8*)(kb + (c0 + n * 16 + lr) * 64 + ks * 32 + g * 8);
#pragma unroll
      for (int m = 0; m < 2; m++)
#pragma unroll
        for (int n = 0; n < 4; n++)
          s[m][n] = __builtin_amdgcn_mfma_f32_16x16x32_bf16(qf[m][ks], kf[n], s[m][n], 0, 0, 0);
    }
    // scale; mask only in the last (diagonal-containing) sub-block
    if (kb2 == nkb2 - 1) {
#pragma unroll
      for (int m = 0; m < 2; m++)
#pragma unroll
        for (int n = 0; n < 4; n++)
#pragma unroll
          for (int r = 0; r < 4; r++) {
            int row = q0 + m * 16 + g * 4 + r;
            int col = c0 + n * 16 + lr;
            s[m][n][r] = (col <= row) ? s[m][n][r] * sc2 : -3.0e38f;
          }
    } else {
#pragma unroll
      for (int m = 0; m < 2; m++)
#pragma unroll
        for (int n = 0; n < 4; n++)
#pragma unroll
          for (int r = 0; r < 4; r++) s[m][n][r] *= sc2;
    }
    // row maxes over all 4 n-frags (one shfl chain per row)
    float mx[2][4];
    float growth = -3.0e38f;
#pragma unroll
    for (int m = 0; m < 2; m++)
#pragma unroll
      for (int r = 0; r < 4; r++) {
        float v = fmaxf(fmaxf(s[m][0][r], s[m][1][r]), fmaxf(s[m][2][r], s[m][3][r]));
#pragma unroll
        for (int off = 8; off; off >>= 1) v = fmaxf(v, __shfl_xor(v, off));
        mx[m][r] = v;
        growth = fmaxf(growth, v - mrow[m][r]);
      }
    // defer-max: rescale only when some row's max grew past THR=8
    if (__any(growth > 8.0f)) {
#pragma unroll
      for (int m = 0; m < 2; m++)
#pragma unroll
        for (int r = 0; r < 4; r++) {
          float mn = fmaxf(mrow[m][r], mx[m][r]);
          float al = exp2f(mrow[m][r] - mn);
          mrow[m][r] = mn;
          lrow[m][r] *= al;
#pragma unroll
          for (int n = 0; n < 4; n++) o[m][n][r] *= al;
        }
    }
    // p = exp2(s - m); row-sum over 4 frags
#pragma unroll
    for (int m = 0; m < 2; m++)
#pragma unroll
      for (int r = 0; r < 4; r++) {
        float rs = 0.0f;
#pragma unroll
        for (int n = 0; n < 4; n++) {
          float p = exp2f(s[m][n][r] - mrow[m][r]);
          s[m][n][r] = p;
          rs += p;
        }
#pragma unroll
        for (int off = 8; off; off >>= 1) rs += __shfl_xor(rs, off);
        lrow[m][r] += rs;
      }
    // P -> LDS (bf16) to reach MFMA A-layout (single wave: no barrier)
#pragma unroll
    for (int m = 0; m < 2; m++)
#pragma unroll
      for (int n = 0; n < 4; n++)
#pragma unroll
        for (int r = 0; r < 4; r++)
          Ps[m * 16 + g * 4 + r][n * 16 + lr] = f2bf(s[m][n][r]);
    // O += P V  (two K=32 slots)
#pragma unroll
    for (int ks = 0; ks < 2; ks++) {
      bf16x8 vf[4];
#pragma unroll
      for (int n = 0; n < 4; n++)
        vf[n] = *(const bf16x8*)(vb + (n * 16 + lr) * 256 + c0 + ks * 32 + g * 8);
#pragma unroll
      for (int m = 0; m < 2; m++) {
        bf16x8 pa = *(const bf16x8*)&Ps[m * 16 + lr][ks * 32 + g * 8];
#pragma unroll
        for (int n = 0; n < 4; n++)
          o[m][n] = __builtin_amdgcn_mfma_f32_16x16x32_bf16(pa, vf[n], o[m][n], 0, 0, 0);
      }
    }
  }
  // finalize + store [b,t,h*64+e]
#pragma unroll
  for (int m = 0; m < 2; m++)
#pragma unroll
    for (int r = 0; r < 4; r++) {
      float inv = 1.0f / lrow[m][r];
      long t = q0 + m * 16 + g * 4 + r;
#pragma unroll
      for (int n = 0; n < 4; n++) {
        long e = n * 16 + lr;
        ao[((long)bb * 256 + t) * 1024 + hh * 64 + e] = f2bf(o[m][n][r] * inv);
      }
    }
}

// ---------------- launch ---------------------------------------------------
// Workspace (MB offsets, 184 MB): wqt@0 wkt@2 wvt@4 (fused N=3072 B^T) wpt@6
// w1t@8 w2t@16; hb@24 (bf16 h, then h2); qbf@56 kbf@88 vtb@120 atb@152.
// yb (bf16 y) reuses qbf@56; ff1@56 (128MB) after LN2. d_out: fp32, FF2 only.
extern "C" void kernel_launch(void* const* d_in, const int* in_sizes, int n_in,
                              void* d_out, int out_size, void* d_ws, size_t ws_size,
                              hipStream_t stream) {
  const float* x     = (const float*)d_in[0];
  const float* ln1g  = (const float*)d_in[1];
  const float* ln1b  = (const float*)d_in[2];
  const float* Wq    = (const float*)d_in[3];
  const float* Wk    = (const float*)d_in[4];
  const float* Wv    = (const float*)d_in[5];
  const float* Wproj = (const float*)d_in[6];
  const float* bproj = (const float*)d_in[7];
  const float* ln2g  = (const float*)d_in[8];
  const float* ln2b  = (const float*)d_in[9];
  const float* W1    = (const float*)d_in[10];
  const float* b1    = (const float*)d_in[11];
  const float* W2    = (const float*)d_in[12];
  const float* b2    = (const float*)d_in[13];

  const long NEED = 184L << 20;
  if (ws_size < (size_t)NEED) {
    fill_k<<<(out_size + 255) / 256, 256, 0, stream>>>((float*)d_out, out_size,
                                                       (float)(ws_size >> 20));
    return;
  }

  char* ws = (char*)d_ws;
  const long MB = 1 << 20;
  ushort_t* wqt = (ushort_t*)(ws + 0 * MB);   // [0,6MB) = fused QKV B^T
  ushort_t* wkt = (ushort_t*)(ws + 2 * MB);
  ushort_t* wvt = (ushort_t*)(ws + 4 * MB);
  ushort_t* wpt = (ushort_t*)(ws + 6 * MB);
  ushort_t* w1t = (ushort_t*)(ws + 8 * MB);
  ushort_t* w2t = (ushort_t*)(ws + 16 * MB);
  ushort_t* hb  = (ushort_t*)(ws + 24 * MB);  // h, later h2 (bf16)
  ushort_t* qbf = (ushort_t*)(ws + 56 * MB);
  ushort_t* kbf = (ushort_t*)(ws + 88 * MB);
  ushort_t* vtb = (ushort_t*)(ws + 120 * MB);
  ushort_t* atb = (ushort_t*)(ws + 152 * MB);
  ushort_t* yb  = (ushort_t*)(ws + 56 * MB);  // y (bf16), reuses qbf
  ushort_t* ff1 = (ushort_t*)(ws + 56 * MB);  // reuses qbf..atb after LN2

  transpose_w<<<dim3(32, 2, 16), 256, 0, stream>>>(Wq, wqt, 1024, 64);
  transpose_w<<<dim3(32, 2, 16), 256, 0, stream>>>(Wk, wkt, 1024, 64);
  transpose_w<<<dim3(32, 2, 16), 256, 0, stream>>>(Wv, wvt, 1024, 64);
  transpose_w<<<dim3(32, 32, 1), 256, 0, stream>>>(Wproj, wpt, 1024, 1024);
  transpose_w<<<dim3(32, 128, 1), 256, 0, stream>>>(W1, w1t, 1024, 4096);
  transpose_w<<<dim3(128, 32, 1), 256, 0, stream>>>(W2, w2t, 4096, 1024);

  // h = LN1(x) -> bf16
  ln_k<false><<<16384, 256, 0, stream>>>(x, ln1g, ln1b, hb);
  // fused q/k/v projection (M=16384, N=3072, K=1024; grid 64x12=768)
  gemm256<4><<<768, 512, 0, stream>>>(hb, wqt, 16384, 3072, 1024, 12,
                                      nullptr, nullptr, nullptr, qbf, kbf, vtb);
  attn_k<<<8192, 64, 0, stream>>>(qbf, kbf, vtb, atb);
  // y = h + attn @ Wproj + bproj  (bf16 out into yb)
  gemm256<5><<<256, 512, 0, stream>>>(atb, wpt, 16384, 1024, 1024, 4,
                                      bproj, hb, nullptr, yb, nullptr, nullptr);
  // h2 = LN2(y) -> hb (h dead)
  ln_k<true><<<16384, 256, 0, stream>>>(yb, ln2g, ln2b, hb);
  // ff1 = relu(h2 @ W1 + b1)  (N=4096; grid 64x16=1024)
  gemm256<3><<<1024, 512, 0, stream>>>(hb, w1t, 16384, 4096, 1024, 16,
                                       b1, nullptr, nullptr, ff1, nullptr, nullptr);
  // out = h2 + ff1 @ W2 + b2  (fp32 into d_out)
  gemm256<6><<<256, 512, 0, stream>>>(ff1, w2t, 16384, 1024, 4096, 4,
                                      b2, hb, (float*)d_out, nullptr, nullptr, nullptr);
}

// Round 16
// 572.963 us; speedup vs baseline: 1.1359x; 1.0045x over previous
//
#include <hip/hip_runtime.h>

typedef __bf16 bf16x8 __attribute__((ext_vector_type(8)));
typedef float f32x4 __attribute__((ext_vector_type(4)));
typedef unsigned short ushort_t;

__device__ __forceinline__ ushort_t f2bf(float f) {
  unsigned int u = __float_as_uint(f);
  u += 0x7fffu + ((u >> 16) & 1u);
  return (ushort_t)(u >> 16);
}
__device__ __forceinline__ float bf2f(ushort_t u) {
  return __uint_as_float(((unsigned int)u) << 16);
}

// async global->LDS, 16 bytes per lane (dest = wave-uniform base + lane*16)
__device__ __forceinline__ void gl_lds16(const ushort_t* g, const char* l) {
  __builtin_amdgcn_global_load_lds(
      (const __attribute__((address_space(1))) void*)g,
      (__attribute__((address_space(3))) void*)l, 16, 0, 0);
}

__global__ __launch_bounds__(256) void fill_k(float* __restrict__ p, long n, float v) {
  long i = (long)blockIdx.x * 256 + threadIdx.x;
  if (i < n) p[i] = v;
}

// ---------------- batched transpose: fp32 Z x R x C  ->  bf16 Z x C x R ----
__global__ __launch_bounds__(256) void transpose_w(const float* __restrict__ in,
                                                   ushort_t* __restrict__ out,
                                                   int R, int C) {
  __shared__ float tile[32][33];
  const float* inb = in + (long)blockIdx.z * R * C;
  ushort_t* outb = out + (long)blockIdx.z * R * C;
  int r0 = blockIdx.x * 32, c0 = blockIdx.y * 32;
  int tx = threadIdx.x & 31, ty = threadIdx.x >> 5;
#pragma unroll
  for (int i = ty; i < 32; i += 8) tile[i][tx] = inb[(long)(r0 + i) * C + (c0 + tx)];
  __syncthreads();
#pragma unroll
  for (int i = ty; i < 32; i += 8) outb[(long)(c0 + i) * R + (r0 + tx)] = f2bf(tile[tx][i]);
}

// ---------------- layernorm: one row (D=1024) per 256-thread block ---------
template <bool BFIN>
__global__ __launch_bounds__(256) void ln_k(const void* __restrict__ xin,
                                            const float* __restrict__ g,
                                            const float* __restrict__ b,
                                            ushort_t* __restrict__ outU) {
  __shared__ float red[8];
  long row = blockIdx.x;
  int tid = threadIdx.x;
  float4 v;
  if constexpr (BFIN) {
    ushort4 u4 = ((const ushort4*)((const ushort_t*)xin + row * 1024))[tid];
    v = make_float4(bf2f(u4.x), bf2f(u4.y), bf2f(u4.z), bf2f(u4.w));
  } else {
    v = ((const float4*)((const float*)xin + row * 1024))[tid];
  }
  float s = v.x + v.y + v.z + v.w;
#pragma unroll
  for (int off = 32; off; off >>= 1) s += __shfl_xor(s, off);
  int w = tid >> 6;
  if ((tid & 63) == 0) red[w] = s;
  __syncthreads();
  float mean = (red[0] + red[1] + red[2] + red[3]) * (1.0f / 1024.0f);
  float dx = v.x - mean, dy = v.y - mean, dz = v.z - mean, dw = v.w - mean;
  float s2 = dx * dx + dy * dy + dz * dz + dw * dw;
#pragma unroll
  for (int off = 32; off; off >>= 1) s2 += __shfl_xor(s2, off);
  if ((tid & 63) == 0) red[4 + w] = s2;
  __syncthreads();
  float var = (red[4] + red[5] + red[6] + red[7]) * (1.0f / 1024.0f);
  float rstd = rsqrtf(var + 1e-5f);
  int c = tid * 4;
  ushort4 u;
  u.x = f2bf(dx * rstd * g[c + 0] + b[c + 0]);
  u.y = f2bf(dy * rstd * g[c + 1] + b[c + 1]);
  u.z = f2bf(dz * rstd * g[c + 2] + b[c + 2]);
  u.w = f2bf(dw * rstd * g[c + 3] + b[c + 3]);
  ((ushort4*)(outU + row * 1024))[tid] = u;
}

// ---------------- 256x256 8-wave 8-phase bf16 GEMM (BK=64) -----------------
// r10 structure but WITHOUT forced lgkmcnt(0)/sched_barrier in phases: the
// compiler emits fine-grained lgkmcnt(N) waits per MFMA operand [m97 asm],
// so early MFMAs overlap tail ds_reads. Counted vmcnt (asm, memory clobber)
// kept for gl_lds->ds_read cross-wave ordering; barriers unchanged.
// Epilogues: 3: bf16 relu(acc+bias)  4: fused QKV (q,k [b,h,t,e]; v [b,h,e,t])
//            5: bf16 acc+bias+res    6: fp32 acc+bias+res -> d_out
template <int EPI>
__global__ __launch_bounds__(512, 2) void gemm256(const ushort_t* __restrict__ A,
                                                  const ushort_t* __restrict__ Bt,
                                                  int M, int N, int K, int NBC,
                                                  const float* __restrict__ bias,
                                                  const ushort_t* __restrict__ resU,
                                                  float* __restrict__ outF,
                                                  ushort_t* __restrict__ outU,
                                                  ushort_t* __restrict__ outU2,
                                                  ushort_t* __restrict__ outU3) {
  __shared__ __align__(16) char lds[131072];
  const int tid = threadIdx.x;
  const int lane = tid & 63;
  const int w = tid >> 6;            // 0..7
  const int wr = w >> 2, wc = w & 3; // 2 x 4 wave grid
  const int g = lane >> 4, lr = lane & 15;
  const int cpx = gridDim.x >> 3;
  const int wg = (blockIdx.x & 7) * cpx + (blockIdx.x >> 3);
  const long m0 = (long)(wg / NBC) * 256;
  const long n0 = (long)(wg % NBC) * 256;
  // staging source (pre-swizzled so linear gl_lds dest yields swizzled LDS)
  const int srow = tid >> 3;                  // 0..63 within an 8KB issue
  const int sslot = (tid & 7) ^ (srow & 7);   // logical 16B slot to fetch
  const ushort_t* sA = A + (m0 + srow) * (long)K + sslot * 8;
  const ushort_t* sB = Bt + (n0 + srow) * (long)K + sslot * 8;
  const int dA = tid * 16;
  const int dB = 32768 + tid * 16;
  // ds_read bases: row-major [256][64]x2B per region, phys slot = log^(row&7)
  const int abase = (wr * 128 + lr) * 128;
  const int bbase = 32768 + (wc * 64 + lr) * 128;
  const int s0 = g ^ (lr & 7);         // ks=0: logical slot g
  const int s1 = (4 + g) ^ (lr & 7);   // ks=1: logical slot 4+g
  const int NT = K >> 6;

  f32x4 acc[8][4] = {};
  bf16x8 aR[4][2], bR[4][2];
  const char* rb;

#define STAGE_A(tile, half) do {                                          \
    const long _ko = (long)(tile) * 64;                                   \
    char* _d = lds + (((tile) & 1) << 16) + ((half) << 14) + dA;          \
    gl_lds16(sA + _ko + (long)(2 * (half)) * 64 * K, _d);                 \
    gl_lds16(sA + _ko + (long)(2 * (half) + 1) * 64 * K, _d + 8192);      \
  } while (0)
#define STAGE_B(tile, half) do {                                          \
    const long _ko = (long)(tile) * 64;                                   \
    char* _d = lds + (((tile) & 1) << 16) + ((half) << 14) + dB;          \
    gl_lds16(sB + _ko + (long)(2 * (half)) * 64 * K, _d);                 \
    gl_lds16(sB + _ko + (long)(2 * (half) + 1) * 64 * K, _d + 8192);      \
  } while (0)
#define RD_A(base_mf) do {                                                \
    _Pragma("unroll") for (int mf = 0; mf < 4; ++mf) {                    \
      aR[mf][0] = *(const bf16x8*)(rb + abase + ((base_mf) + mf) * 2048 + s0 * 16); \
      aR[mf][1] = *(const bf16x8*)(rb + abase + ((base_mf) + mf) * 2048 + s1 * 16); \
    } } while (0)
#define RD_B2(base_nf) do {                                               \
    _Pragma("unroll") for (int nf = 0; nf < 2; ++nf) {                    \
      bR[(base_nf) + nf][0] = *(const bf16x8*)(rb + bbase + ((base_nf) + nf) * 2048 + s0 * 16); \
      bR[(base_nf) + nf][1] = *(const bf16x8*)(rb + bbase + ((base_nf) + nf) * 2048 + s1 * 16); \
    } } while (0)
#define QUAD(MB, NB) do {                                                 \
    __builtin_amdgcn_s_setprio(1);                                        \
    _Pragma("unroll") for (int mf = 0; mf < 4; ++mf)                      \
      _Pragma("unroll") for (int nf = 0; nf < 2; ++nf) {                  \
        acc[(MB) + mf][(NB) + nf] = __builtin_amdgcn_mfma_f32_16x16x32_bf16(aR[mf][0], bR[(NB) + nf][0], acc[(MB) + mf][(NB) + nf], 0, 0, 0); \
        acc[(MB) + mf][(NB) + nf] = __builtin_amdgcn_mfma_f32_16x16x32_bf16(aR[mf][1], bR[(NB) + nf][1], acc[(MB) + mf][(NB) + nf], 0, 0, 0); \
      }                                                                   \
    __builtin_amdgcn_s_setprio(0); } while (0)

  // ---- prologue: 7 half-tiles, oldest-first; drain tile 0 (8 loads) ----
  STAGE_B(0, 0); STAGE_B(0, 1); STAGE_A(0, 0); STAGE_A(0, 1);
  STAGE_B(1, 0); STAGE_B(1, 1); STAGE_A(1, 0);
  asm volatile("s_waitcnt vmcnt(6)" ::: "memory");
  __builtin_amdgcn_s_barrier();

  for (int t = 0; t < NT; t += 2) {
    const bool s2 = (t + 2 < NT), s3 = (t + 3 < NT);
    // ===================== tile t (buf0) =====================
    rb = lds;
    RD_A(0);
    RD_B2(0);
    STAGE_A(t + 1, 1);
    __builtin_amdgcn_s_barrier();
    QUAD(0, 0);
    __builtin_amdgcn_s_barrier();
    RD_B2(2);
    __builtin_amdgcn_s_barrier();
    QUAD(0, 2);
    __builtin_amdgcn_s_barrier();
    if (s2) STAGE_B(t + 2, 0);
    RD_A(4);
    __builtin_amdgcn_s_barrier();
    QUAD(4, 2);
    __builtin_amdgcn_s_barrier();
    if (s2) { STAGE_B(t + 2, 1); STAGE_A(t + 2, 0); }
    __builtin_amdgcn_s_barrier();
    QUAD(4, 0);
    if (s2) asm volatile("s_waitcnt vmcnt(6)" ::: "memory");
    else    asm volatile("s_waitcnt vmcnt(0)" ::: "memory");
    __builtin_amdgcn_s_barrier();
    // ===================== tile t+1 (buf1) =====================
    rb = lds + 65536;
    RD_A(0);
    RD_B2(0);
    if (s2) STAGE_A(t + 2, 1);
    __builtin_amdgcn_s_barrier();
    QUAD(0, 0);
    __builtin_amdgcn_s_barrier();
    RD_B2(2);
    __builtin_amdgcn_s_barrier();
    QUAD(0, 2);
    __builtin_amdgcn_s_barrier();
    if (s3) STAGE_B(t + 3, 0);
    RD_A(4);
    __builtin_amdgcn_s_barrier();
    QUAD(4, 2);
    __builtin_amdgcn_s_barrier();
    if (s3) { STAGE_B(t + 3, 1); STAGE_A(t + 3, 0); }
    __builtin_amdgcn_s_barrier();
    QUAD(4, 0);
    if (s3) asm volatile("s_waitcnt vmcnt(6)" ::: "memory");
    else    asm volatile("s_waitcnt vmcnt(0)" ::: "memory");
    __builtin_amdgcn_s_barrier();
  }
#undef STAGE_A
#undef STAGE_B
#undef RD_A
#undef RD_B2
#undef QUAD

  // ---- epilogue. C/D frag layout col=lr, row=g*4+r [m89].
  if constexpr (EPI == 3 || EPI == 5) {
    ushort_t* l16 = (ushort_t*)lds;
#pragma unroll
    for (int mf = 0; mf < 8; ++mf)
#pragma unroll
      for (int nf = 0; nf < 4; ++nf) {
        int col = wc * 64 + nf * 16 + lr;
        long gcol = n0 + col;
#pragma unroll
        for (int r = 0; r < 4; ++r) {
          int row = wr * 128 + mf * 16 + g * 4 + r;
          float v = acc[mf][nf][r] + bias[gcol];
          if constexpr (EPI == 3) v = fmaxf(v, 0.0f);
          else v += bf2f(resU[(m0 + row) * (long)N + gcol]);
          l16[row * 256 + (col ^ (g << 3))] = f2bf(v);
        }
      }
    __syncthreads();
#pragma unroll
    for (int k = 0; k < 16; ++k) {
      int c = tid + k * 512;
      int tt = c >> 5, off = c & 31;
      int pc = (off * 8) ^ ((((unsigned)tt >> 2) & 3) << 3);
      uint4 d = *(uint4*)&l16[tt * 256 + pc];
      *(uint4*)&outU[(m0 + tt) * (long)N + n0 + off * 8] = d;
    }
  } else if constexpr (EPI == 6) {
#pragma unroll
    for (int mf = 0; mf < 8; ++mf)
#pragma unroll
      for (int nf = 0; nf < 4; ++nf)
#pragma unroll
        for (int r = 0; r < 4; ++r) {
          long row = m0 + wr * 128 + mf * 16 + g * 4 + r;
          long col = n0 + wc * 64 + nf * 16 + lr;
          long i = row * (long)N + col;
          outF[i] = acc[mf][nf][r] + bias[col] + bf2f(resU[i]);
        }
  } else {  // EPI == 4: fused QKV
    const int p = (int)(n0 >> 10);       // block-uniform: which of q/k/v
    const long bb2 = m0 >> 8;
    if (p < 2) {
      ushort_t* dst = (p == 0) ? outU : outU2;
      ushort_t* l16 = (ushort_t*)lds;
#pragma unroll
      for (int mf = 0; mf < 8; ++mf)
#pragma unroll
        for (int nf = 0; nf < 4; ++nf) {
          int col = wc * 64 + nf * 16 + lr;
#pragma unroll
          for (int r = 0; r < 4; ++r) {
            int row = wr * 128 + mf * 16 + g * 4 + r;
            l16[row * 256 + (col ^ (g << 3))] = f2bf(acc[mf][nf][r]);
          }
        }
      __syncthreads();
      const int hh0 = (int)((n0 & 1023) >> 6);
#pragma unroll
      for (int k = 0; k < 16; ++k) {
        int c = tid + k * 512;
        int hh_l = c >> 11, tt = (c >> 3) & 255, off = c & 7;
        int col = hh_l * 64 + off * 8;
        int pc = col ^ ((((unsigned)tt >> 2) & 3) << 3);
        uint4 d = *(uint4*)&l16[tt * 256 + pc];
        *(uint4*)&dst[(((bb2 * 16 + hh0 + hh_l) * 256 + tt) << 6) + off * 8] = d;
      }
    } else {
      // V third: transpose 256x256 tile through LDS, then coalesced stores.
      unsigned int* l32 = (unsigned int*)lds;
#pragma unroll
      for (int mf = 0; mf < 8; ++mf)
#pragma unroll
        for (int nf = 0; nf < 4; ++nf)
#pragma unroll
          for (int r2 = 0; r2 < 2; ++r2) {
            int row = wr * 128 + mf * 16 + g * 4 + r2 * 2;  // local tt (even)
            int col = wc * 64 + nf * 16 + lr;               // local v-col
            unsigned int pk = (unsigned int)f2bf(acc[mf][nf][r2 * 2]) |
                              ((unsigned int)f2bf(acc[mf][nf][r2 * 2 + 1]) << 16);
            l32[col * 128 + ((row >> 1) ^ ((col & 7) << 2))] = pk;
          }
      __syncthreads();
      const long vcol0 = (n0 & 1023);
#pragma unroll
      for (int k = 0; k < 16; ++k) {
        int c = tid + k * 512;           // 8192 16B-chunks total
        int e_l = c >> 5, k16 = c & 31;  // e-row, chunk within 512B row
        uint4 d = *(uint4*)&l32[e_l * 128 + ((k16 * 4) ^ ((e_l & 7) << 2))];
        long vc = vcol0 + e_l;
        long hh = vc >> 6, e = vc & 63;
        *(uint4*)&outU3[(((bb2 * 16 + hh) * 64 + e) << 8) + k16 * 8] = d;
      }
    }
  }
}

// ---------------- flash attention: 1 wave per (32 q rows, b, h) ------------
// KVBLK=64 (r15 proven): one softmax chain per 64 KV cols.
__global__ __launch_bounds__(64, 3) void attn_k(const ushort_t* __restrict__ q,
                                                const ushort_t* __restrict__ k,
                                                const ushort_t* __restrict__ vt,
                                                ushort_t* __restrict__ ao) {
  __shared__ __align__(16) ushort_t Ps[32][72];
  const int lane = threadIdx.x;
  const int g = lane >> 4, lr = lane & 15;
  const int blk = blockIdx.x;
  const int q8 = blk & 7;          // which 32-row q block
  const int bh = blk >> 3;
  const int bb = bh >> 4, hh = bh & 15;
  const int q0 = q8 * 32;
  const ushort_t* qb = q + (long)bh * 256 * 64;
  const ushort_t* kb = k + (long)bh * 256 * 64;
  const ushort_t* vb = vt + (long)bh * 64 * 256;
  bf16x8 qf[2][2];
#pragma unroll
  for (int m = 0; m < 2; m++)
#pragma unroll
    for (int ks = 0; ks < 2; ks++)
      qf[m][ks] = *(const bf16x8*)(qb + (q0 + m * 16 + lr) * 64 + ks * 32 + g * 8);
  f32x4 o[2][4] = {};
  float mrow[2][4], lrow[2][4];
#pragma unroll
  for (int m = 0; m < 2; m++)
#pragma unroll
    for (int r = 0; r < 4; r++) { mrow[m][r] = -3.0e38f; lrow[m][r] = 0.0f; }
  const float sc2 = 0.04508422f;   // (1/32) * log2(e): softmax in exp2 domain
  const int nkb2 = (q8 >> 1) + 1;  // KV-64 blocks needed for rows < q0+32
  for (int kb2 = 0; kb2 < nkb2; kb2++) {
    const int c0 = kb2 * 64;
    f32x4 s[2][4] = {};
#pragma unroll
    for (int ks = 0; ks < 2; ks++) {
      bf16x8 kf[4];
#pragma unroll
      for (int n = 0; n < 4; n++)
        kf[n] = *(const bf16x8*)(kb + (c0 + n * 16 + lr) * 64 + ks * 32 + g * 8);
#pragma unroll
      for (int m = 0; m < 2; m++)
#pragma unroll
        for (int n = 0; n < 4; n++)
          s[m][n] = __builtin_amdgcn_mfma_f32_16x16x32_bf16(qf[m][ks], kf[n], s[m][n], 0, 0, 0);
    }
    if (kb2 == nkb2 - 1) {
#pragma unroll
      for (int m = 0; m < 2; m++)
#pragma unroll
        for (int n = 0; n < 4; n++)
#pragma unroll
          for (int r = 0; r < 4; r++) {
            int row = q0 + m * 16 + g * 4 + r;
            int col = c0 + n * 16 + lr;
            s[m][n][r] = (col <= row) ? s[m][n][r] * sc2 : -3.0e38f;
          }
    } else {
#pragma unroll
      for (int m = 0; m < 2; m++)
#pragma unroll
        for (int n = 0; n < 4; n++)
#pragma unroll
          for (int r = 0; r < 4; r++) s[m][n][r] *= sc2;
    }
    float mx[2][4];
    float growth = -3.0e38f;
#pragma unroll
    for (int m = 0; m < 2; m++)
#pragma unroll
      for (int r = 0; r < 4; r++) {
        float v = fmaxf(fmaxf(s[m][0][r], s[m][1][r]), fmaxf(s[m][2][r], s[m][3][r]));
#pragma unroll
        for (int off = 8; off; off >>= 1) v = fmaxf(v, __shfl_xor(v, off));
        mx[m][r] = v;
        growth = fmaxf(growth, v - mrow[m][r]);
      }
    if (__any(growth > 8.0f)) {
#pragma unroll
      for (int m = 0; m < 2; m++)
#pragma unroll
        for (int r = 0; r < 4; r++) {
          float mn = fmaxf(mrow[m][r], mx[m][r]);
          float al = exp2f(mrow[m][r] - mn);
          mrow[m][r] = mn;
          lrow[m][r] *= al;
#pragma unroll
          for (int n = 0; n < 4; n++) o[m][n][r] *= al;
        }
    }
#pragma unroll
    for (int m = 0; m < 2; m++)
#pragma unroll
      for (int r = 0; r < 4; r++) {
        float rs = 0.0f;
#pragma unroll
        for (int n = 0; n < 4; n++) {
          float p = exp2f(s[m][n][r] - mrow[m][r]);
          s[m][n][r] = p;
          rs += p;
        }
#pragma unroll
        for (int off = 8; off; off >>= 1) rs += __shfl_xor(rs, off);
        lrow[m][r] += rs;
      }
#pragma unroll
    for (int m = 0; m < 2; m++)
#pragma unroll
      for (int n = 0; n < 4; n++)
#pragma unroll
        for (int r = 0; r < 4; r++)
          Ps[m * 16 + g * 4 + r][n * 16 + lr] = f2bf(s[m][n][r]);
#pragma unroll
    for (int ks = 0; ks < 2; ks++) {
      bf16x8 vf[4];
#pragma unroll
      for (int n = 0; n < 4; n++)
        vf[n] = *(const bf16x8*)(vb + (n * 16 + lr) * 256 + c0 + ks * 32 + g * 8);
#pragma unroll
      for (int m = 0; m < 2; m++) {
        bf16x8 pa = *(const bf16x8*)&Ps[m * 16 + lr][ks * 32 + g * 8];
#pragma unroll
        for (int n = 0; n < 4; n++)
          o[m][n] = __builtin_amdgcn_mfma_f32_16x16x32_bf16(pa, vf[n], o[m][n], 0, 0, 0);
      }
    }
  }
#pragma unroll
  for (int m = 0; m < 2; m++)
#pragma unroll
    for (int r = 0; r < 4; r++) {
      float inv = 1.0f / lrow[m][r];
      long t = q0 + m * 16 + g * 4 + r;
#pragma unroll
      for (int n = 0; n < 4; n++) {
        long e = n * 16 + lr;
        ao[((long)bb * 256 + t) * 1024 + hh * 64 + e] = f2bf(o[m][n][r] * inv);
      }
    }
}

// ---------------- launch ---------------------------------------------------
// Workspace (MB offsets, 184 MB): wqt@0 wkt@2 wvt@4 (fused N=3072 B^T) wpt@6
// w1t@8 w2t@16; hb@24 (bf16 h, then h2); qbf@56 kbf@88 vtb@120 atb@152.
// yb (bf16 y) reuses qbf@56; ff1@56 (128MB) after LN2. d_out: fp32, FF2 only.
extern "C" void kernel_launch(void* const* d_in, const int* in_sizes, int n_in,
                              void* d_out, int out_size, void* d_ws, size_t ws_size,
                              hipStream_t stream) {
  const float* x     = (const float*)d_in[0];
  const float* ln1g  = (const float*)d_in[1];
  const float* ln1b  = (const float*)d_in[2];
  const float* Wq    = (const float*)d_in[3];
  const float* Wk    = (const float*)d_in[4];
  const float* Wv    = (const float*)d_in[5];
  const float* Wproj = (const float*)d_in[6];
  const float* bproj = (const float*)d_in[7];
  const float* ln2g  = (const float*)d_in[8];
  const float* ln2b  = (const float*)d_in[9];
  const float* W1    = (const float*)d_in[10];
  const float* b1    = (const float*)d_in[11];
  const float* W2    = (const float*)d_in[12];
  const float* b2    = (const float*)d_in[13];

  const long NEED = 184L << 20;
  if (ws_size < (size_t)NEED) {
    fill_k<<<(out_size + 255) / 256, 256, 0, stream>>>((float*)d_out, out_size,
                                                       (float)(ws_size >> 20));
    return;
  }

  char* ws = (char*)d_ws;
  const long MB = 1 << 20;
  ushort_t* wqt = (ushort_t*)(ws + 0 * MB);   // [0,6MB) = fused QKV B^T
  ushort_t* wkt = (ushort_t*)(ws + 2 * MB);
  ushort_t* wvt = (ushort_t*)(ws + 4 * MB);
  ushort_t* wpt = (ushort_t*)(ws + 6 * MB);
  ushort_t* w1t = (ushort_t*)(ws + 8 * MB);
  ushort_t* w2t = (ushort_t*)(ws + 16 * MB);
  ushort_t* hb  = (ushort_t*)(ws + 24 * MB);  // h, later h2 (bf16)
  ushort_t* qbf = (ushort_t*)(ws + 56 * MB);
  ushort_t* kbf = (ushort_t*)(ws + 88 * MB);
  ushort_t* vtb = (ushort_t*)(ws + 120 * MB);
  ushort_t* atb = (ushort_t*)(ws + 152 * MB);
  ushort_t* yb  = (ushort_t*)(ws + 56 * MB);  // y (bf16), reuses qbf
  ushort_t* ff1 = (ushort_t*)(ws + 56 * MB);  // reuses qbf..atb after LN2

  transpose_w<<<dim3(32, 2, 16), 256, 0, stream>>>(Wq, wqt, 1024, 64);
  transpose_w<<<dim3(32, 2, 16), 256, 0, stream>>>(Wk, wkt, 1024, 64);
  transpose_w<<<dim3(32, 2, 16), 256, 0, stream>>>(Wv, wvt, 1024, 64);
  transpose_w<<<dim3(32, 32, 1), 256, 0, stream>>>(Wproj, wpt, 1024, 1024);
  transpose_w<<<dim3(32, 128, 1), 256, 0, stream>>>(W1, w1t, 1024, 4096);
  transpose_w<<<dim3(128, 32, 1), 256, 0, stream>>>(W2, w2t, 4096, 1024);

  // h = LN1(x) -> bf16
  ln_k<false><<<16384, 256, 0, stream>>>(x, ln1g, ln1b, hb);
  // fused q/k/v projection (M=16384, N=3072, K=1024; grid 64x12=768)
  gemm256<4><<<768, 512, 0, stream>>>(hb, wqt, 16384, 3072, 1024, 12,
                                      nullptr, nullptr, nullptr, qbf, kbf, vtb);
  attn_k<<<8192, 64, 0, stream>>>(qbf, kbf, vtb, atb);
  // y = h + attn @ Wproj + bproj  (bf16 out into yb)
  gemm256<5><<<256, 512, 0, stream>>>(atb, wpt, 16384, 1024, 1024, 4,
                                      bproj, hb, nullptr, yb, nullptr, nullptr);
  // h2 = LN2(y) -> hb (h dead)
  ln_k<true><<<16384, 256, 0, stream>>>(yb, ln2g, ln2b, hb);
  // ff1 = relu(h2 @ W1 + b1)  (N=4096; grid 64x16=1024)
  gemm256<3><<<1024, 512, 0, stream>>>(hb, w1t, 16384, 4096, 1024, 16,
                                       b1, nullptr, nullptr, ff1, nullptr, nullptr);
  // out = h2 + ff1 @ W2 + b2  (fp32 into d_out)
  gemm256<6><<<256, 512, 0, stream>>>(ff1, w2t, 16384, 1024, 4096, 4,
                                      b2, hb, (float*)d_out, nullptr, nullptr, nullptr);
}